// Round 2
// baseline (868.025 us; speedup 1.0000x reference)
//
#include <hip/hip_runtime.h>

#define NPTS 65536
#define VW 176
#define VD 132
#define FD 32

typedef _Float16 half8 __attribute__((ext_vector_type(8)));
typedef _Float16 h16x4 __attribute__((ext_vector_type(4)));
typedef float f32x4 __attribute__((ext_vector_type(4)));

// fp16 weight cache layout (offsets in halfs), lives in d_ws
#define OFF_WQ 0
#define OFF_L1 4096                      // layers 1..8: OFF_L1 + (l-1)*16384
#define OFF_L9 (4096 + 8 * 16384)        // W9 rows 0..255
#define W16_TOTAL (4096 + 8 * 16384 + 32768)

struct Params {
    const float* W[10];
    const float* b[10];
};

__device__ __forceinline__ float sp100(float x) {
    if (x > 0.2f) return x;
    float e = __expf(x * 100.0f);
    return __logf(1.0f + e) * 0.01f;
}

// ---------------- Kernel P: fp32 -> fp16 weight cache ----------------
__global__ __launch_bounds__(256) void prep_kernel(Params P, const float* __restrict__ Wq,
                                                   _Float16* __restrict__ w16) {
    const int i = blockIdx.x * 256 + threadIdx.x;
    if (i >= W16_TOTAL) return;
    if (i < 4096) { w16[i] = (_Float16)Wq[i]; return; }
    int j = i - 4096;
    if (j < 8 * 16384) {
        const int l = (j >> 14) + 1;
        const int r = (j & 16383) >> 7;
        float v = 0.0f;
        if (l != 4) v = P.W[l][j & 16383];
        else if (r < 125) v = P.W[4][j & 16383];   // pad rows 125..127 with 0
        w16[i] = (_Float16)v;
        return;
    }
    j -= 8 * 16384;
    w16[i] = (_Float16)P.W[9][j];                  // W9 rows 0..255
}

// ---------------- Kernel A: query layer -> feat16[N,32] (pure gather) ----------------
// 32 lanes per point (lane = feature f), 8 points per 256-thread block.
__global__ __launch_bounds__(256) void query_kernel(
    const float* __restrict__ pixel, const float* __restrict__ vol,
    _Float16* __restrict__ feat_out)
{
    const int tid = threadIdx.x;
    const int f = tid & 31;
    const int p = blockIdx.x * 8 + (tid >> 5);

    const float qx = pixel[p*3+0] + 24.0f;
    const float qy = pixel[p*3+1] + 24.0f;
    const float qz = (pixel[p*3+2] - 425.0f) / 480.0f * 128.0f;
    const int bx = (int)floorf(qx);
    const int by = (int)floorf(qy);
    const int bz = (int)floorf(qz);

    // sim normalization cancels in feat normalization -> use raw sim.
    float mix0 = 0.0f, mix1 = 0.0f;   // 2 accumulators for ILP
    #pragma unroll
    for (int dx = 0; dx < 4; ++dx) {
        const int i0 = bx + dx - 1;
        const float sx = (float)i0 * qx;
        #pragma unroll
        for (int dy = 0; dy < 4; ++dy) {
            const int i1 = by + dy - 1;
            const int rowbase = (i0 * VW + i1) * VD;
            const float sxy = sx + (float)i1 * qy;
            #pragma unroll
            for (int dz = 0; dz < 4; ++dz) {
                const int i2 = bz + dz - 1;
                const float sim = sxy + (float)i2 * qz;
                const float v = vol[(rowbase + i2) * FD + f];
                if (dx < 2) mix0 = fmaf(sim, v, mix0);
                else        mix1 = fmaf(sim, v, mix1);
            }
        }
    }
    const float mixed = mix0 + mix1;
    float tot = mixed;
    #pragma unroll
    for (int m = 16; m >= 1; m >>= 1) tot += __shfl_xor(tot, m, 32);
    feat_out[p*32 + f] = (_Float16)(mixed / tot);
}

// ---------------- Kernel A2: sum|Wq@feat+bq| via MFMA ----------------
// 64-lane wave handles 16 points; 4 waves per block; one atomic per block.
__global__ __launch_bounds__(256) void bias_kernel(
    const _Float16* __restrict__ feat16, const _Float16* __restrict__ w16,
    const float* __restrict__ bq, float* __restrict__ sum_abs)
{
    const int tid  = threadIdx.x;
    const int lane = tid & 63;
    const int wid  = tid >> 6;
    const int n16  = lane & 15;
    const int kg   = lane >> 4;
    const int gm   = blockIdx.x * 64 + wid * 16;

    const half8 fa = *(const half8*)&feat16[(size_t)(gm + n16) * 32 + kg * 8];
    float s = 0.0f;
    #pragma unroll
    for (int ot = 0; ot < 8; ++ot) {
        const half8 wqf = *(const half8*)&w16[OFF_WQ + (ot*16 + n16) * 32 + kg * 8];
        f32x4 z = {};
        const f32x4 acc = __builtin_amdgcn_mfma_f32_16x16x32_f16(wqf, fa, z, 0, 0, 0);
        const int f0 = ot*16 + kg*4;
        const f32x4 bqv = *(const f32x4*)&bq[f0];
        #pragma unroll
        for (int r = 0; r < 4; ++r) s += fabsf(acc[r] + bqv[r]);
    }
    #pragma unroll
    for (int m = 32; m >= 1; m >>= 1) s += __shfl_xor(s, m, 64);
    __shared__ float part[4];
    if (lane == 0) part[wid] = s;
    __syncthreads();
    if (tid == 0) atomicAdd(sum_abs, part[0] + part[1] + part[2] + part[3]);
}

// ---------------- Kernel B: MLP, fp16 MFMA ----
// 256 threads = 4 independent waves; wave owns 16 points. No __syncthreads:
// act LDS region is wave-private (all writes/reads stay within the wave's rows).
// Layers 0..8 use SWAPPED operands (A=weights, B=act): each lane owns 4
// consecutive features of ONE point -> packed ds_write_b64 epilogue.
// Layer 9 keeps the original order so global stores stay in 64B segments.
__global__ __launch_bounds__(256, 4) void mlp_kernel(
    const float* __restrict__ world, const _Float16* __restrict__ feat16,
    const _Float16* __restrict__ w16, const float* __restrict__ bq,
    const float* __restrict__ sum_abs, float* __restrict__ out, Params P)
{
    __shared__ __align__(16) _Float16 act[64 * 136];

    const int tid  = threadIdx.x;
    const int lane = tid & 63;
    const int wid  = tid >> 6;
    const int n16  = lane & 15;          // point (B.n / C.col for l0..8); A.m for l9
    const int kg   = lane >> 4;          // k-group / C.row-group
    const int wrow0 = wid * 16;          // wave's local row base in act
    const int gm    = blockIdx.x * 64 + wrow0;  // wave's global point base
    const float inv_mean = (float)NPTS * 128.0f / sum_abs[0];

    // this lane's point coords (used by layer 0 and the layer-4 skip)
    const float wx = world[(size_t)(gm + n16)*3 + 0];
    const float wy = world[(size_t)(gm + n16)*3 + 1];
    const float wz = world[(size_t)(gm + n16)*3 + 2];

    const int arow  = (wrow0 + n16) * 136;   // this lane's point row in act
    const int a_off = arow + kg * 8;

    // ---- layer 0: bias = feat@Wq^T+bq via swapped MFMA; h = world@W0^T+b0 scalar ----
    {
        const half8 fa = *(const half8*)&feat16[(size_t)(gm + n16) * 32 + kg * 8];
        f32x4 acc[8];
        #pragma unroll
        for (int ot = 0; ot < 8; ++ot) {
            const half8 wqf = *(const half8*)&w16[OFF_WQ + (ot*16 + n16) * 32 + kg * 8];
            f32x4 z = {};
            acc[ot] = __builtin_amdgcn_mfma_f32_16x16x32_f16(wqf, fa, z, 0, 0, 0);
        }
        #pragma unroll
        for (int ot = 0; ot < 8; ++ot) {
            const int f0 = ot*16 + kg*4;               // multiple of 4
            const f32x4 b0v = *(const f32x4*)&P.b[0][f0];
            const f32x4 bqv = *(const f32x4*)&bq[f0];
            const f32x4 wA = *(const f32x4*)&P.W[0][f0*3 + 0];
            const f32x4 wB = *(const f32x4*)&P.W[0][f0*3 + 4];
            const f32x4 wC = *(const f32x4*)&P.W[0][f0*3 + 8];
            const float w0v[12] = {wA[0],wA[1],wA[2],wA[3],
                                   wB[0],wB[1],wB[2],wB[3],
                                   wC[0],wC[1],wC[2],wC[3]};
            h16x4 hv;
            #pragma unroll
            for (int r = 0; r < 4; ++r) {
                const float h = b0v[r] + w0v[3*r]*wx + w0v[3*r+1]*wy + w0v[3*r+2]*wz;
                const float bias = acc[ot][r] + bqv[r];
                hv[r] = (_Float16)sp100(h * bias * inv_mean);
            }
            *(h16x4*)&act[arow + f0] = hv;             // 8B aligned
        }
    }

    // ---- layers 1..8 ----
    #pragma unroll 1
    for (int l = 1; l <= 8; ++l) {
        const _Float16* wl = &w16[OFF_L1 + (l - 1) * 16384];
        half8 a[4];
        #pragma unroll
        for (int c = 0; c < 4; ++c) a[c] = *(const half8*)&act[a_off + c*32];

        f32x4 acc[8] = {};
        #pragma unroll
        for (int c = 0; c < 4; ++c) {
            #pragma unroll
            for (int ot = 0; ot < 8; ++ot) {
                const half8 bf = *(const half8*)&wl[(ot*16 + n16)*128 + kg*8 + c*32];
                acc[ot] = __builtin_amdgcn_mfma_f32_16x16x32_f16(bf, a[c], acc[ot], 0, 0, 0);
            }
        }
        if (l != 4) {
            #pragma unroll
            for (int ot = 0; ot < 8; ++ot) {
                const int f0 = ot*16 + kg*4;
                const f32x4 bl4 = *(const f32x4*)&P.b[l][f0];
                h16x4 hv;
                #pragma unroll
                for (int r = 0; r < 4; ++r) hv[r] = (_Float16)sp100(acc[ot][r] + bl4[r]);
                *(h16x4*)&act[arow + f0] = hv;
            }
        } else {
            // guarded scalar bias (b[4] has only 125 entries) + skip-concat of world
            #pragma unroll
            for (int ot = 0; ot < 8; ++ot) {
                const int f0 = ot*16 + kg*4;
                h16x4 hv;
                #pragma unroll
                for (int r = 0; r < 4; ++r) {
                    const int f = f0 + r;
                    float v;
                    if (f < 125) v = acc[ot][r] + P.b[4][f];
                    else         v = (f == 125) ? wx : (f == 126) ? wy : wz;
                    hv[r] = (_Float16)sp100(v);
                }
                *(h16x4*)&act[arow + f0] = hv;
            }
        }
    }

    // ---- layer 9: 257 outputs = two 128-col MFMA halves (ORIGINAL operand order,
    //      so stores land as 4x64B segments) + scalar col 256 ----
    {
        half8 a[4];
        #pragma unroll
        for (int c = 0; c < 4; ++c) a[c] = *(const half8*)&act[a_off + c*32];

        #pragma unroll 1
        for (int hh = 0; hh < 2; ++hh) {
            f32x4 acc[8] = {};
            #pragma unroll
            for (int c = 0; c < 4; ++c) {
                #pragma unroll
                for (int ot = 0; ot < 8; ++ot) {
                    const half8 bf = *(const half8*)&w16[OFF_L9 + (hh*128 + ot*16 + n16)*128 + kg*8 + c*32];
                    acc[ot] = __builtin_amdgcn_mfma_f32_16x16x32_f16(a[c], bf, acc[ot], 0, 0, 0);
                }
            }
            #pragma unroll
            for (int ot = 0; ot < 8; ++ot) {
                const int col = ot*16 + n16;
                const float b9 = P.b[9][hh*128 + col];
                #pragma unroll
                for (int r = 0; r < 4; ++r) {
                    out[(size_t)(gm + kg*4 + r)*257 + hh*128 + col] = acc[ot][r] + b9;
                }
            }
        }
    }
    // col 256: 4 lanes per point, 32 k each, shuffle-reduce
    {
        const int rr = lane >> 2;       // 0..15: local row
        const int q  = lane & 3;
        float s = 0.0f;
        #pragma unroll
        for (int j = 0; j < 32; ++j) {
            const int k = q*32 + j;
            s = fmaf((float)act[(wrow0 + rr)*136 + k], P.W[9][256*128 + k], s);
        }
        s += __shfl_xor(s, 1, 64);
        s += __shfl_xor(s, 2, 64);
        if (q == 0) out[(size_t)(gm + rr)*257 + 256] = P.b[9][256] + s;
    }
}

extern "C" void kernel_launch(void* const* d_in, const int* in_sizes, int n_in,
                              void* d_out, int out_size, void* d_ws, size_t ws_size,
                              hipStream_t stream) {
    const float* world = (const float*)d_in[0];
    const float* pixel = (const float*)d_in[1];
    const float* vol   = (const float*)d_in[2];
    const float* Wq    = (const float*)d_in[3];
    const float* bq    = (const float*)d_in[4];
    Params P;
    for (int l = 0; l < 10; ++l) {
        P.W[l] = (const float*)d_in[5 + 2*l];
        P.b[l] = (const float*)d_in[6 + 2*l];
    }
    float*    sum_abs = (float*)d_ws;
    _Float16* feat16  = (_Float16*)((char*)d_ws + 4096);
    _Float16* w16     = (_Float16*)((char*)d_ws + 4096 + (size_t)NPTS * 32 * 2);

    hipMemsetAsync(d_ws, 0, 256, stream);
    prep_kernel<<<(W16_TOTAL + 255) / 256, 256, 0, stream>>>(P, Wq, w16);
    query_kernel<<<NPTS / 8, 256, 0, stream>>>(pixel, vol, feat16);
    bias_kernel<<<NPTS / 64, 256, 0, stream>>>(feat16, w16, bq, sum_abs);
    mlp_kernel<<<NPTS / 64, 256, 0, stream>>>(world, feat16, w16, bq, sum_abs,
                                              (float*)d_out, P);
}